// Round 11
// baseline (6660.635 us; speedup 1.0000x reference)
//
#include <hip/hip_runtime.h>
#include <hip/hip_bf16.h>
#include <stdint.h>

#define BB 4
#define NN 16384
#define SS 1024
#define KSAMP 64
#define DD 256
#define CIN 259
#define HH 512
#define R2C 0.04f

// workspace offsets (bytes, all 256-aligned)
#define OFF_PTS  0ull            // bf16 pointsT [B][N][256]  33,554,432
#define OFF_Q    33554432ull     // f32 point norms [B][N]       262,144
#define OFF_W1P  33816576ull     // bf16 packed w1               294,912
#define OFF_W2P  34111488ull     // bf16 packed w2               524,288
#define OFF_CX   34635776ull     // f32 centers x [4096]
#define OFF_CY   34652160ull
#define OFF_CZ   34668544ull
#define OFF_PROG 34684928ull     // int prog[4]                       16 B
#define OFF_SEQ  34684992ull     // int seq[4][4]                     64 B
#define OFF_KSL  34685056ull     // u64 ksl[4][2][4] (parity dbuf)   256 B

typedef __attribute__((ext_vector_type(8))) short bf16x8;
typedef __attribute__((ext_vector_type(4))) short bf16x4;
typedef __attribute__((ext_vector_type(4))) float f32x4;

__device__ __forceinline__ unsigned short f2bf(float f) {
    unsigned u = __float_as_uint(f);
    u = u + 0x7fffu + ((u >> 16) & 1u);   // round-to-nearest-even
    return (unsigned short)(u >> 16);
}

// ---------------------------------------------------------------------------
// Kernel A: points transpose->bf16 (blocks 0..1023) + point norms
//           (1024..1087) + weight packing (1088,1089). Runs first, ~40 us.
// ---------------------------------------------------------------------------
__global__ __launch_bounds__(1024) void k_prep2(const float* __restrict__ xyz,
                                                const float* __restrict__ pts,
                                                const float* __restrict__ w1,
                                                const float* __restrict__ w2,
                                                unsigned char* __restrict__ ws)
{
    __shared__ __align__(16) unsigned char smem[64 * 264 * 2];
    const int blk = blockIdx.x;
    const int t   = threadIdx.x;

    if (blk < 1024) {
        // ---------------- transpose points -> bf16 rows --------------------
        const int b  = blk >> 8;
        const int n0 = (blk & 255) << 6;      // 64 points per tile
        unsigned short* sT = (unsigned short*)smem;  // [64][264]
        const int tn = t & 63, tc = t >> 6;   // tc 0..15
        for (int cc = tc; cc < 256; cc += 16) {
            float v = pts[((size_t)(b * 256 + cc)) * NN + n0 + tn];
            sT[tn * 264 + cc] = f2bf(v);
        }
        __syncthreads();
        unsigned short* ptsT = (unsigned short*)(ws + OFF_PTS);
        const int r = t >> 4, part = t & 15;  // 16 shorts per thread
        size_t ob = (((size_t)b * NN) + n0 + r) * 256 + part * 16;
        bf16x8* dst = (bf16x8*)(ptsT + ob);
        const bf16x8* src = (const bf16x8*)(sT + r * 264 + part * 16);
        dst[0] = src[0];
        dst[1] = src[1];
    } else if (blk < 1088) {
        // ---------------- point squared norms ------------------------------
        const int qb = blk - 1024;
        const int b = qb >> 4;
        const int n = ((qb & 15) << 10) + t;
        const float* xb = xyz + (size_t)b * 3 * NN;
        float X = xb[n], Y = xb[NN + n], Z = xb[2 * NN + n];
        float q = __fadd_rn(__fadd_rn(__fmul_rn(X, X), __fmul_rn(Y, Y)), __fmul_rn(Z, Z));
        ((float*)(ws + OFF_Q))[b * NN + n] = q;
    } else if (blk == 1088) {
        // ---------------- pack w1 into MFMA-B fragment order ---------------
        unsigned short* w1p = (unsigned short*)(ws + OFF_W1P);
        for (int e = t; e < 32 * 9 * 64 * 8; e += 1024) {
            int j = e & 7, lane = (e >> 3) & 63, rest = e >> 9;
            int kt = rest % 9, nt = rest / 9;
            int kk = kt * 32 + 4 * (lane >> 4) + (j & 3) + 16 * (j >> 2);
            int o  = nt * 16 + (lane & 15);
            float v = 0.f;
            if (kk < CIN) {
                int c = (kk < 256) ? (kk + 3) : (kk - 256);
                v = w1[o * CIN + c];
            }
            w1p[e] = f2bf(v);
        }
    } else {
        unsigned short* w2p = (unsigned short*)(ws + OFF_W2P);
        for (int e = t; e < 32 * 16 * 64 * 8; e += 1024) {
            int j = e & 7, lane = (e >> 3) & 63, rest = e >> 9;
            int kt = rest & 15, nt = rest >> 4;
            int kk = kt * 32 + 4 * (lane >> 4) + (j & 3) + 16 * (j >> 2);
            int o  = nt * 16 + (lane & 15);
            w2p[e] = f2bf(w2[o * 512 + kk]);
        }
    }
}

// ---------------------------------------------------------------------------
// Kernel B: blocks 0..15 = FPS producers (4 groups x 4 batches; 4096 pts per
//           group -> 16 floats/thread state, register-resident). Per-iter
//           cross-group sync: parity-dbuf key slots + monotonic seq (agent).
//           blocks 16..4111 = per-(b,s) consumers.
// LDS map (producer): sK [0,256) u64[2][16] | sWidx [256,260)
// LDS map (consumer): sFeat [0,37888) | sH1 [37888,104448) | sIdx [104448,104704)
// ---------------------------------------------------------------------------
__global__ __launch_bounds__(1024) void k_fused(const float* __restrict__ xyz,
                                                const float* __restrict__ b1,
                                                const float* __restrict__ b2,
                                                unsigned char* __restrict__ ws,
                                                float* __restrict__ out)
{
    __shared__ __align__(16) unsigned char smem[104832];
    const int blk = blockIdx.x;
    const int t   = threadIdx.x;
    int* prog = (int*)(ws + OFF_PROG);
    float* cxs = (float*)(ws + OFF_CX);
    float* cys = (float*)(ws + OFF_CY);
    float* czs = (float*)(ws + OFF_CZ);

    if (blk < 16) {
        // ================= FPS producer, batch b, group g ==================
        const int b = blk >> 2, g = blk & 3;
        const float* xb = xyz + (size_t)b * 3 * NN;
        float x[4], y[4], z[4], d[4];
        const int base = (g << 12) + t;       // group owns [g*4096,(g+1)*4096)
#pragma unroll
        for (int k = 0; k < 4; k++) {
            const int n = base + (k << 10);
            x[k] = xb[n];
            y[k] = xb[NN + n];
            z[k] = xb[2 * NN + n];
            d[k] = 1e10f;
        }
        int* seqb = (int*)(ws + OFF_SEQ) + (b << 2);                  // [4]
        unsigned long long* kslb = (unsigned long long*)(ws + OFF_KSL) + (b << 3);
        unsigned long long* sK = (unsigned long long*)smem;           // [2][16]
        int* sWidx = (int*)(smem + 256);
        const int wv = t >> 6, lane = t & 63;
        // initial farthest = b (uniform broadcast load)
        float cx = xb[b], cy = xb[NN + b], cz = xb[2 * NN + b];

        for (int it = 0; it < SS; ++it) {
            if (g == 0 && t == 0) {
                // publish center via agent-scope atomics (coherence point)
                __hip_atomic_store(&cxs[(b << 10) + it], cx, __ATOMIC_RELAXED,
                                   __HIP_MEMORY_SCOPE_AGENT);
                __hip_atomic_store(&cys[(b << 10) + it], cy, __ATOMIC_RELAXED,
                                   __HIP_MEMORY_SCOPE_AGENT);
                __hip_atomic_store(&czs[(b << 10) + it], cz, __ATOMIC_RELAXED,
                                   __HIP_MEMORY_SCOPE_AGENT);
                if ((it & 7) == 0)
                    __hip_atomic_store(&prog[b], it, __ATOMIC_RELEASE,
                                       __HIP_MEMORY_SCOPE_AGENT);
            }
            if (it == SS - 1) break;

            // local distance update + argmax (strict > keeps FIRST index;
            // n ascends with k for fixed t)
            float bl = -1.0f;
            int   bi = 0;
#pragma unroll
            for (int k = 0; k < 4; k++) {
                float dx = __fsub_rn(x[k], cx);
                float dy = __fsub_rn(y[k], cy);
                float dz = __fsub_rn(z[k], cz);
                float s  = __fadd_rn(__fadd_rn(__fmul_rn(dx, dx), __fmul_rn(dy, dy)),
                                     __fmul_rn(dz, dz));
                float nd = fminf(d[k], s);
                d[k] = nd;
                if (nd > bl) { bl = nd; bi = base + (k << 10); }
            }
            // wave reduce: max distance, then min index among achievers
            float bm = bl;
#pragma unroll
            for (int off = 1; off < 64; off <<= 1)
                bm = fmaxf(bm, __shfl_xor(bm, off));
            int cand = (bl == bm) ? bi : 0x7fffffff;
#pragma unroll
            for (int off = 1; off < 64; off <<= 1)
                cand = min(cand, __shfl_xor(cand, off));
            // packed key: high = dist bits (nonneg -> monotone), low = ~idx
            unsigned long long wkey =
                ((unsigned long long)__float_as_uint(bm) << 32) |
                (unsigned)(0xFFFFFFFFu - (unsigned)cand);
            if (lane == 0) sK[((it & 1) << 4) + wv] = wkey;
            __syncthreads();

            // cross-wave: 16 slots lane-parallel + 4-step u64 max
            unsigned long long gk = sK[((it & 1) << 4) + (lane & 15)];
#pragma unroll
            for (int off = 1; off < 16; off <<= 1) {
                unsigned long long o = __shfl_xor(gk, off);
                if (o > gk) gk = o;
            }
            // post block partial (parity-dbuf slot), then release seq
            unsigned long long* slot = kslb + ((it & 1) << 2);
            if (wv == 0 && lane == 0) {
                __hip_atomic_store(&slot[g], gk, __ATOMIC_RELAXED,
                                   __HIP_MEMORY_SCOPE_AGENT);
                __hip_atomic_store(&seqb[g], it + 1, __ATOMIC_RELEASE,
                                   __HIP_MEMORY_SCOPE_AGENT);
            }
            if (wv == 0) {
                // poll all 4 groups' seq (acquire), then combine keys
                for (;;) {
                    int sv = (lane < 4)
                        ? __hip_atomic_load(&seqb[lane], __ATOMIC_ACQUIRE,
                                            __HIP_MEMORY_SCOPE_AGENT)
                        : (it + 1);
                    if (__all(sv == it + 1)) break;
                    __builtin_amdgcn_s_sleep(1);
                }
                unsigned long long kj = (lane < 4)
                    ? __hip_atomic_load(&slot[lane], __ATOMIC_RELAXED,
                                        __HIP_MEMORY_SCOPE_AGENT)
                    : 0ull;
#pragma unroll
                for (int off = 1; off < 4; off <<= 1) {
                    unsigned long long o = __shfl_xor(kj, off);
                    if (o > kj) kj = o;
                }
                if (lane == 0) *sWidx = (int)(0xFFFFFFFFu - (unsigned)kj);
            }
            __syncthreads();
            const int widx = *sWidx;
            // winner coords from global at uniform address (cache-hot,
            // bit-identical to the originally loaded values)
            cx = xb[widx]; cy = xb[NN + widx]; cz = xb[2 * NN + widx];
        }
        // final: all centers written -> release everything
        if (g == 0 && t == 0)
            __hip_atomic_store(&prog[b], SS, __ATOMIC_RELEASE,
                               __HIP_MEMORY_SCOPE_AGENT);
        return;
    }

    // ==================== consumer block: (b, s) ===========================
    const int i = blk - 16;
    const int b = i & 3, s = i >> 2;
    const int cs = (b << 10) + s;

    unsigned short* sFeat = (unsigned short*)smem;            // [64][296] = 37,888 B
    unsigned short* sH1   = (unsigned short*)(smem + 37888);  // [64][520] = 66,560 B
    int*            sIdx  = (int*)(smem + 104448);            // [64]      =    256 B

    // ---- phase 0: wait until center s is published (prog init = -1) ----
    if (t == 0) {
        while (__hip_atomic_load(&prog[b], __ATOMIC_ACQUIRE,
                                 __HIP_MEMORY_SCOPE_AGENT) <= s)
            __builtin_amdgcn_s_sleep(8);
    }
    __syncthreads();

    // read center via agent atomics (coherence point; ordered by release)
    const float cx = __hip_atomic_load(&cxs[cs], __ATOMIC_RELAXED,
                                       __HIP_MEMORY_SCOPE_AGENT);
    const float cy = __hip_atomic_load(&cys[cs], __ATOMIC_RELAXED,
                                       __HIP_MEMORY_SCOPE_AGENT);
    const float cz = __hip_atomic_load(&czs[cs], __ATOMIC_RELAXED,
                                       __HIP_MEMORY_SCOPE_AGENT);
    const float* xb = xyz + (size_t)b * 3 * NN;

    // ---- phase 1: ball query (wave 0 only) -> sIdx ----
    if (t < 64) {
        const int lane = t;
        const float* Q = (const float*)(ws + OFF_Q) + b * NN;
        const float qc = __fadd_rn(__fadd_rn(__fmul_rn(cx, cx), __fmul_rn(cy, cy)),
                                   __fmul_rn(cz, cz));
        int collected = 0;
        int first = -1;
        for (int c = 0; c < 256; c++) {
            const int n = (c << 6) + lane;
            float px = xb[n], py = xb[NN + n], pz = xb[2 * NN + n], qj = Q[n];
            float dot = __fadd_rn(__fadd_rn(__fmul_rn(cx, px), __fmul_rn(cy, py)),
                                  __fmul_rn(cz, pz));
            float r = __fsub_rn(__fadd_rn(qc, qj), __fmul_rn(2.0f, dot));
            bool valid = !(r > R2C);
            unsigned long long m = __ballot(valid);
            if (m) {
                if (first < 0) first = (c << 6) + __builtin_ctzll(m);
                int rank = __popcll(m & ((1ull << lane) - 1ull));
                int slot = collected + rank;
                if (valid && slot < 64) sIdx[slot] = n;
                collected += __popcll(m);
                if (collected >= 64) break;
            }
        }
        if (collected < 64) {
            for (int k = collected + lane; k < 64; k += 64) sIdx[k] = first;
        }
    }
    __syncthreads();

    // ---- phase 2: gather features (FULL 256 shorts per point) ----
    {
        const unsigned short* ptsT = (const unsigned short*)(ws + OFF_PTS);
        const int k = t >> 4, part = t & 15;   // 64 pts x 16 parts x 16 shorts
        const int n = sIdx[k];
        const bf16x8* src = (const bf16x8*)(ptsT + ((size_t)b * NN + n) * 256 + part * 16);
        bf16x8* dst = (bf16x8*)(sFeat + k * 296 + part * 16);
        dst[0] = src[0];
        dst[1] = src[1];
    }
    if (t < 64) {
        const int n = sIdx[t];
        sFeat[t * 296 + 256] = f2bf(__fsub_rn(xb[n], cx));
        sFeat[t * 296 + 257] = f2bf(__fsub_rn(xb[NN + n], cy));
        sFeat[t * 296 + 258] = f2bf(__fsub_rn(xb[2 * NN + n], cz));
#pragma unroll
        for (int c = 259; c < 288; c++) sFeat[t * 296 + c] = 0;
    }
    __syncthreads();

    const int wv = t >> 6, lane = t & 63;
    const int l15 = lane & 15, g = lane >> 4;

    f32x4 acc[4][2];
#pragma unroll
    for (int a = 0; a < 4; a++)
#pragma unroll
        for (int j = 0; j < 2; j++) acc[a][j] = (f32x4){0.f, 0.f, 0.f, 0.f};

    // ---- layer 1: K = 288 (9 ktiles); 16 waves x 2 ntiles ----
    const bf16x8* w1v = (const bf16x8*)(ws + OFF_W1P);
    for (int kt = 0; kt < 9; kt++) {
        bf16x8 af[4];
#pragma unroll
        for (int mt = 0; mt < 4; mt++) {
            const unsigned short* p = sFeat + (mt * 16 + l15) * 296 + kt * 32 + 4 * g;
            bf16x4 lo = *(const bf16x4*)p;
            bf16x4 hi = *(const bf16x4*)(p + 16);
            af[mt] = __builtin_shufflevector(lo, hi, 0, 1, 2, 3, 4, 5, 6, 7);
        }
        bf16x8 bfr[2];
#pragma unroll
        for (int nti = 0; nti < 2; nti++)
            bfr[nti] = w1v[((wv * 2 + nti) * 9 + kt) * 64 + lane];
#pragma unroll
        for (int mt = 0; mt < 4; mt++)
#pragma unroll
            for (int nti = 0; nti < 2; nti++)
                acc[mt][nti] = __builtin_amdgcn_mfma_f32_16x16x32_bf16(
                    af[mt], bfr[nti], acc[mt][nti], 0, 0, 0);
    }
    // epilogue 1: bias + swish -> sH1 (bf16)
#pragma unroll
    for (int mt = 0; mt < 4; mt++)
#pragma unroll
        for (int nti = 0; nti < 2; nti++) {
            const int o = (wv * 2 + nti) * 16 + l15;
            const float bias = b1[o];
#pragma unroll
            for (int r = 0; r < 4; r++) {
                float v = acc[mt][nti][r] + bias;
                float sw = v / (1.f + __expf(-v));
                sH1[(mt * 16 + g * 4 + r) * 520 + o] = f2bf(sw);
            }
        }
    __syncthreads();

    // ---- layer 2: K = 512 (16 ktiles) ----
#pragma unroll
    for (int a = 0; a < 4; a++)
#pragma unroll
        for (int j = 0; j < 2; j++) acc[a][j] = (f32x4){0.f, 0.f, 0.f, 0.f};

    const bf16x8* w2v = (const bf16x8*)(ws + OFF_W2P);
    for (int kt = 0; kt < 16; kt++) {
        bf16x8 af[4];
#pragma unroll
        for (int mt = 0; mt < 4; mt++) {
            const unsigned short* p = sH1 + (mt * 16 + l15) * 520 + kt * 32 + 4 * g;
            bf16x4 lo = *(const bf16x4*)p;
            bf16x4 hi = *(const bf16x4*)(p + 16);
            af[mt] = __builtin_shufflevector(lo, hi, 0, 1, 2, 3, 4, 5, 6, 7);
        }
        bf16x8 bfr[2];
#pragma unroll
        for (int nti = 0; nti < 2; nti++)
            bfr[nti] = w2v[((wv * 2 + nti) * 16 + kt) * 64 + lane];
#pragma unroll
        for (int mt = 0; mt < 4; mt++)
#pragma unroll
            for (int nti = 0; nti < 2; nti++)
                acc[mt][nti] = __builtin_amdgcn_mfma_f32_16x16x32_bf16(
                    af[mt], bfr[nti], acc[mt][nti], 0, 0, 0);
    }
    // epilogue 2: bias + swish + mean over the 64 samples
#pragma unroll
    for (int nti = 0; nti < 2; nti++) {
        float tot = 0.f;
        const int o = (wv * 2 + nti) * 16 + l15;
        const float bias = b2[o];
#pragma unroll
        for (int mt = 0; mt < 4; mt++) {
#pragma unroll
            for (int r = 0; r < 4; r++) {
                float v = acc[mt][nti][r] + bias;
                tot += v / (1.f + __expf(-v));
            }
        }
        tot += __shfl_xor(tot, 16);
        tot += __shfl_xor(tot, 32);
        if (lane < 16) {
            const int oo = (wv * 2 + nti) * 16 + lane;
            out[((size_t)b * 512 + oo) * 1024 + s] = tot * 0.015625f;
        }
    }
}

extern "C" void kernel_launch(void* const* d_in, const int* in_sizes, int n_in,
                              void* d_out, int out_size, void* d_ws, size_t ws_size,
                              hipStream_t stream)
{
    const float* xyz = (const float*)d_in[0];
    const float* pts = (const float*)d_in[1];
    const float* w1  = (const float*)d_in[2];
    const float* b1  = (const float*)d_in[3];
    const float* w2  = (const float*)d_in[4];
    const float* b2  = (const float*)d_in[5];
    float* out = (float*)d_out;
    unsigned char* ws = (unsigned char*)d_ws;

    // prog must start negative (blocks consumers); seq must start at 0
    hipMemsetAsync((void*)(ws + OFF_PROG), 0xFF, 16, stream);
    hipMemsetAsync((void*)(ws + OFF_SEQ), 0x00, 64, stream);
    k_prep2<<<1090, 1024, 0, stream>>>(xyz, pts, w1, w2, ws);
    k_fused<<<4112, 1024, 0, stream>>>(xyz, b1, b2, ws, out);
}

// Round 12
// 1759.541 us; speedup vs baseline: 3.7854x; 3.7854x over previous
//
#include <hip/hip_runtime.h>
#include <hip/hip_bf16.h>
#include <stdint.h>

#define BB 4
#define NN 16384
#define SS 1024
#define KSAMP 64
#define DD 256
#define CIN 259
#define HH 512
#define R2C 0.04f

// workspace offsets (bytes, all 256-aligned)
#define OFF_PTS  0ull            // bf16 pointsT [B][N][256]  33,554,432
#define OFF_Q    33554432ull     // f32 point norms [B][N]       262,144
#define OFF_W1P  33816576ull     // bf16 packed w1               294,912
#define OFF_W2P  34111488ull     // bf16 packed w2               524,288
#define OFF_CX   34635776ull     // f32 centers x [4096]
#define OFF_CY   34652160ull
#define OFF_CZ   34668544ull
#define OFF_PROG 34684928ull     // int prog[4*16] (one 64-B line per batch)

typedef __attribute__((ext_vector_type(8))) short bf16x8;
typedef __attribute__((ext_vector_type(4))) short bf16x4;
typedef __attribute__((ext_vector_type(4))) float f32x4;

__device__ __forceinline__ unsigned short f2bf(float f) {
    unsigned u = __float_as_uint(f);
    u = u + 0x7fffu + ((u >> 16) & 1u);   // round-to-nearest-even
    return (unsigned short)(u >> 16);
}

// ---------------------------------------------------------------------------
// Kernel A: points transpose->bf16 (blocks 0..1023) + point norms
//           (1024..1087) + weight packing (1088,1089). Runs first, ~40 us.
// ---------------------------------------------------------------------------
__global__ __launch_bounds__(1024) void k_prep2(const float* __restrict__ xyz,
                                                const float* __restrict__ pts,
                                                const float* __restrict__ w1,
                                                const float* __restrict__ w2,
                                                unsigned char* __restrict__ ws)
{
    __shared__ __align__(16) unsigned char smem[64 * 264 * 2];
    const int blk = blockIdx.x;
    const int t   = threadIdx.x;

    if (blk < 1024) {
        // ---------------- transpose points -> bf16 rows --------------------
        const int b  = blk >> 8;
        const int n0 = (blk & 255) << 6;      // 64 points per tile
        unsigned short* sT = (unsigned short*)smem;  // [64][264]
        const int tn = t & 63, tc = t >> 6;   // tc 0..15
        for (int cc = tc; cc < 256; cc += 16) {
            float v = pts[((size_t)(b * 256 + cc)) * NN + n0 + tn];
            sT[tn * 264 + cc] = f2bf(v);
        }
        __syncthreads();
        unsigned short* ptsT = (unsigned short*)(ws + OFF_PTS);
        const int r = t >> 4, part = t & 15;  // 16 shorts per thread
        size_t ob = (((size_t)b * NN) + n0 + r) * 256 + part * 16;
        bf16x8* dst = (bf16x8*)(ptsT + ob);
        const bf16x8* src = (const bf16x8*)(sT + r * 264 + part * 16);
        dst[0] = src[0];
        dst[1] = src[1];
    } else if (blk < 1088) {
        // ---------------- point squared norms ------------------------------
        const int qb = blk - 1024;
        const int b = qb >> 4;
        const int n = ((qb & 15) << 10) + t;
        const float* xb = xyz + (size_t)b * 3 * NN;
        float X = xb[n], Y = xb[NN + n], Z = xb[2 * NN + n];
        float q = __fadd_rn(__fadd_rn(__fmul_rn(X, X), __fmul_rn(Y, Y)), __fmul_rn(Z, Z));
        ((float*)(ws + OFF_Q))[b * NN + n] = q;
    } else if (blk == 1088) {
        // ---------------- pack w1 into MFMA-B fragment order ---------------
        unsigned short* w1p = (unsigned short*)(ws + OFF_W1P);
        for (int e = t; e < 32 * 9 * 64 * 8; e += 1024) {
            int j = e & 7, lane = (e >> 3) & 63, rest = e >> 9;
            int kt = rest % 9, nt = rest / 9;
            int kk = kt * 32 + 4 * (lane >> 4) + (j & 3) + 16 * (j >> 2);
            int o  = nt * 16 + (lane & 15);
            float v = 0.f;
            if (kk < CIN) {
                int c = (kk < 256) ? (kk + 3) : (kk - 256);
                v = w1[o * CIN + c];
            }
            w1p[e] = f2bf(v);
        }
    } else {
        unsigned short* w2p = (unsigned short*)(ws + OFF_W2P);
        for (int e = t; e < 32 * 16 * 64 * 8; e += 1024) {
            int j = e & 7, lane = (e >> 3) & 63, rest = e >> 9;
            int kt = rest & 15, nt = rest >> 4;
            int kk = kt * 32 + 4 * (lane >> 4) + (j & 3) + 16 * (j >> 2);
            int o  = nt * 16 + (lane & 15);
            w2p[e] = f2bf(w2[o * 512 + kk]);
        }
    }
}

// ---------------------------------------------------------------------------
// Kernel B: blocks 0..3 = FPS producers (round-1 FPS core + LDS-ring batched
//           center publication: flush 8 centers + 1 release per 8 iters).
//           blocks 4..4099 = per-(b,s) consumers.
// LDS map (producer): sC[3]/sWMax[16]/sWin @ [0,96) | ring [128,224)
// LDS map (consumer): sFeat [0,37888) | sH1 [37888,104448) | sIdx [104448,104704)
// ---------------------------------------------------------------------------
__global__ __launch_bounds__(1024) void k_fused(const float* __restrict__ xyz,
                                                const float* __restrict__ b1,
                                                const float* __restrict__ b2,
                                                unsigned char* __restrict__ ws,
                                                float* __restrict__ out)
{
    __shared__ __align__(16) unsigned char smem[104832];
    const int blk = blockIdx.x;
    const int t   = threadIdx.x;
    int* prog = (int*)(ws + OFF_PROG);   // prog[b*16]: one 64-B line per batch
    float* cxs = (float*)(ws + OFF_CX);
    float* cys = (float*)(ws + OFF_CY);
    float* czs = (float*)(ws + OFF_CZ);

    if (blk < 4) {
        // ================= FPS producer, batch b = blk (round-1 core) ======
        const int b = blk;
        const float* xb = xyz + (size_t)b * 3 * NN;
        float x[16], y[16], z[16], d[16];
        const int base = t * 16;
        const float4* xv = (const float4*)(xb + base);
        const float4* yv = (const float4*)(xb + NN + base);
        const float4* zv = (const float4*)(xb + 2 * NN + base);
#pragma unroll
        for (int i = 0; i < 4; i++) {
            float4 a = xv[i]; x[4*i]=a.x; x[4*i+1]=a.y; x[4*i+2]=a.z; x[4*i+3]=a.w;
            float4 c = yv[i]; y[4*i]=c.x; y[4*i+1]=c.y; y[4*i+2]=c.z; y[4*i+3]=c.w;
            float4 e = zv[i]; z[4*i]=e.x; z[4*i+1]=e.y; z[4*i+2]=e.z; z[4*i+3]=e.w;
        }
#pragma unroll
        for (int i = 0; i < 16; i++) d[i] = 1e10f;

        float* sC    = (float*)smem;          // [3] centroid
        float* sWMax = (float*)smem + 4;      // [16]
        int*   sWin  = (int*)((float*)smem + 20);
        float* ring  = (float*)(smem + 128);  // [8][3] center ring (t0 only)

        // initial farthest = b (b < 16 -> owner thread 0)
        if (t == (b >> 4)) {
#pragma unroll
            for (int k = 0; k < 16; k++)
                if ((b & 15) == k) { sC[0] = x[k]; sC[1] = y[k]; sC[2] = z[k]; }
        }
        __syncthreads();

        for (int it = 0; it < SS; ++it) {
            const float cx = sC[0], cy = sC[1], cz = sC[2];
            if (t == 0) {
                // flush previous 8 centers (ring slots 0..7 hold it-8..it-1)
                if ((it & 7) == 0 && it > 0) {
                    const int q0 = (b << 10) + it - 8;
#pragma unroll
                    for (int j = 0; j < 8; j++) {
                        __hip_atomic_store(&cxs[q0 + j], ring[3*j+0],
                                           __ATOMIC_RELAXED, __HIP_MEMORY_SCOPE_AGENT);
                        __hip_atomic_store(&cys[q0 + j], ring[3*j+1],
                                           __ATOMIC_RELAXED, __HIP_MEMORY_SCOPE_AGENT);
                        __hip_atomic_store(&czs[q0 + j], ring[3*j+2],
                                           __ATOMIC_RELAXED, __HIP_MEMORY_SCOPE_AGENT);
                    }
                    // release: centers <= it-1 now visible; consumers s<it go
                    __hip_atomic_store(&prog[b << 4], it, __ATOMIC_RELEASE,
                                       __HIP_MEMORY_SCOPE_AGENT);
                }
                // record this iteration's center in the ring
                ring[3 * (it & 7) + 0] = cx;
                ring[3 * (it & 7) + 1] = cy;
                ring[3 * (it & 7) + 2] = cz;
                *sWin = 0x7fffffff;
            }
            if (it == SS - 1) break;

            float bl = -1.0f;
#pragma unroll
            for (int k = 0; k < 16; k++) {
                float dx = __fsub_rn(x[k], cx);
                float dy = __fsub_rn(y[k], cy);
                float dz = __fsub_rn(z[k], cz);
                float s  = __fadd_rn(__fadd_rn(__fmul_rn(dx, dx), __fmul_rn(dy, dy)),
                                     __fmul_rn(dz, dz));
                float nd = fminf(d[k], s);
                d[k] = nd;
                bl = fmaxf(bl, nd);
            }
            float bm = bl;
#pragma unroll
            for (int off = 32; off; off >>= 1) bm = fmaxf(bm, __shfl_xor(bm, off));
            if ((t & 63) == 0) sWMax[t >> 6] = bm;
            __syncthreads();

            float gm = sWMax[0];
#pragma unroll
            for (int wv = 1; wv < 16; wv++) gm = fmaxf(gm, sWMax[wv]);

            if (bl == gm) {
                int cand = 0x7fffffff;
#pragma unroll
                for (int k = 15; k >= 0; k--) if (d[k] == gm) cand = base + k;
                atomicMin(sWin, cand);
            }
            __syncthreads();
            const int w = *sWin;
            if (t == (w >> 4)) {
                const int wk = w & 15;
#pragma unroll
                for (int k = 0; k < 16; k++)
                    if (wk == k) { sC[0] = x[k]; sC[1] = y[k]; sC[2] = z[k]; }
            }
            __syncthreads();
        }
        // tail: publish remaining ring (iters SS-8..SS-1), then full release
        if (t == 0) {
            const int q0 = (b << 10) + SS - 8;
#pragma unroll
            for (int j = 0; j < 8; j++) {
                __hip_atomic_store(&cxs[q0 + j], ring[3*j+0],
                                   __ATOMIC_RELAXED, __HIP_MEMORY_SCOPE_AGENT);
                __hip_atomic_store(&cys[q0 + j], ring[3*j+1],
                                   __ATOMIC_RELAXED, __HIP_MEMORY_SCOPE_AGENT);
                __hip_atomic_store(&czs[q0 + j], ring[3*j+2],
                                   __ATOMIC_RELAXED, __HIP_MEMORY_SCOPE_AGENT);
            }
            __hip_atomic_store(&prog[b << 4], SS, __ATOMIC_RELEASE,
                               __HIP_MEMORY_SCOPE_AGENT);
        }
        return;
    }

    // ==================== consumer block: (b, s) ===========================
    const int i = blk - 4;
    const int b = i & 3, s = i >> 2;
    const int cs = (b << 10) + s;

    unsigned short* sFeat = (unsigned short*)smem;            // [64][296] = 37,888 B
    unsigned short* sH1   = (unsigned short*)(smem + 37888);  // [64][520] = 66,560 B
    int*            sIdx  = (int*)(smem + 104448);            // [64]      =    256 B

    // ---- phase 0: wait until center s is published (prog init = -1) ----
    if (t == 0) {
        while (__hip_atomic_load(&prog[b << 4], __ATOMIC_ACQUIRE,
                                 __HIP_MEMORY_SCOPE_AGENT) <= s)
            __builtin_amdgcn_s_sleep(32);
    }
    __syncthreads();

    // read center via agent atomics (coherence point; ordered by release)
    const float cx = __hip_atomic_load(&cxs[cs], __ATOMIC_RELAXED,
                                       __HIP_MEMORY_SCOPE_AGENT);
    const float cy = __hip_atomic_load(&cys[cs], __ATOMIC_RELAXED,
                                       __HIP_MEMORY_SCOPE_AGENT);
    const float cz = __hip_atomic_load(&czs[cs], __ATOMIC_RELAXED,
                                       __HIP_MEMORY_SCOPE_AGENT);
    const float* xb = xyz + (size_t)b * 3 * NN;

    // ---- phase 1: ball query (wave 0 only) -> sIdx ----
    if (t < 64) {
        const int lane = t;
        const float* Q = (const float*)(ws + OFF_Q) + b * NN;
        const float qc = __fadd_rn(__fadd_rn(__fmul_rn(cx, cx), __fmul_rn(cy, cy)),
                                   __fmul_rn(cz, cz));
        int collected = 0;
        int first = -1;
        for (int c = 0; c < 256; c++) {
            const int n = (c << 6) + lane;
            float px = xb[n], py = xb[NN + n], pz = xb[2 * NN + n], qj = Q[n];
            float dot = __fadd_rn(__fadd_rn(__fmul_rn(cx, px), __fmul_rn(cy, py)),
                                  __fmul_rn(cz, pz));
            float r = __fsub_rn(__fadd_rn(qc, qj), __fmul_rn(2.0f, dot));
            bool valid = !(r > R2C);
            unsigned long long m = __ballot(valid);
            if (m) {
                if (first < 0) first = (c << 6) + __builtin_ctzll(m);
                int rank = __popcll(m & ((1ull << lane) - 1ull));
                int slot = collected + rank;
                if (valid && slot < 64) sIdx[slot] = n;
                collected += __popcll(m);
                if (collected >= 64) break;
            }
        }
        if (collected < 64) {
            for (int k = collected + lane; k < 64; k += 64) sIdx[k] = first;
        }
    }
    __syncthreads();

    // ---- phase 2: gather features (FULL 256 shorts per point) ----
    {
        const unsigned short* ptsT = (const unsigned short*)(ws + OFF_PTS);
        const int k = t >> 4, part = t & 15;   // 64 pts x 16 parts x 16 shorts
        const int n = sIdx[k];
        const bf16x8* src = (const bf16x8*)(ptsT + ((size_t)b * NN + n) * 256 + part * 16);
        bf16x8* dst = (bf16x8*)(sFeat + k * 296 + part * 16);
        dst[0] = src[0];
        dst[1] = src[1];
    }
    if (t < 64) {
        const int n = sIdx[t];
        sFeat[t * 296 + 256] = f2bf(__fsub_rn(xb[n], cx));
        sFeat[t * 296 + 257] = f2bf(__fsub_rn(xb[NN + n], cy));
        sFeat[t * 296 + 258] = f2bf(__fsub_rn(xb[2 * NN + n], cz));
#pragma unroll
        for (int c = 259; c < 288; c++) sFeat[t * 296 + c] = 0;
    }
    __syncthreads();

    const int wv = t >> 6, lane = t & 63;
    const int l15 = lane & 15, g = lane >> 4;

    f32x4 acc[4][2];
#pragma unroll
    for (int a = 0; a < 4; a++)
#pragma unroll
        for (int j = 0; j < 2; j++) acc[a][j] = (f32x4){0.f, 0.f, 0.f, 0.f};

    // ---- layer 1: K = 288 (9 ktiles); 16 waves x 2 ntiles ----
    const bf16x8* w1v = (const bf16x8*)(ws + OFF_W1P);
    for (int kt = 0; kt < 9; kt++) {
        bf16x8 af[4];
#pragma unroll
        for (int mt = 0; mt < 4; mt++) {
            const unsigned short* p = sFeat + (mt * 16 + l15) * 296 + kt * 32 + 4 * g;
            bf16x4 lo = *(const bf16x4*)p;
            bf16x4 hi = *(const bf16x4*)(p + 16);
            af[mt] = __builtin_shufflevector(lo, hi, 0, 1, 2, 3, 4, 5, 6, 7);
        }
        bf16x8 bfr[2];
#pragma unroll
        for (int nti = 0; nti < 2; nti++)
            bfr[nti] = w1v[((wv * 2 + nti) * 9 + kt) * 64 + lane];
#pragma unroll
        for (int mt = 0; mt < 4; mt++)
#pragma unroll
            for (int nti = 0; nti < 2; nti++)
                acc[mt][nti] = __builtin_amdgcn_mfma_f32_16x16x32_bf16(
                    af[mt], bfr[nti], acc[mt][nti], 0, 0, 0);
    }
    // epilogue 1: bias + swish -> sH1 (bf16)
#pragma unroll
    for (int mt = 0; mt < 4; mt++)
#pragma unroll
        for (int nti = 0; nti < 2; nti++) {
            const int o = (wv * 2 + nti) * 16 + l15;
            const float bias = b1[o];
#pragma unroll
            for (int r = 0; r < 4; r++) {
                float v = acc[mt][nti][r] + bias;
                float sw = v / (1.f + __expf(-v));
                sH1[(mt * 16 + g * 4 + r) * 520 + o] = f2bf(sw);
            }
        }
    __syncthreads();

    // ---- layer 2: K = 512 (16 ktiles) ----
#pragma unroll
    for (int a = 0; a < 4; a++)
#pragma unroll
        for (int j = 0; j < 2; j++) acc[a][j] = (f32x4){0.f, 0.f, 0.f, 0.f};

    const bf16x8* w2v = (const bf16x8*)(ws + OFF_W2P);
    for (int kt = 0; kt < 16; kt++) {
        bf16x8 af[4];
#pragma unroll
        for (int mt = 0; mt < 4; mt++) {
            const unsigned short* p = sH1 + (mt * 16 + l15) * 520 + kt * 32 + 4 * g;
            bf16x4 lo = *(const bf16x4*)p;
            bf16x4 hi = *(const bf16x4*)(p + 16);
            af[mt] = __builtin_shufflevector(lo, hi, 0, 1, 2, 3, 4, 5, 6, 7);
        }
        bf16x8 bfr[2];
#pragma unroll
        for (int nti = 0; nti < 2; nti++)
            bfr[nti] = w2v[((wv * 2 + nti) * 16 + kt) * 64 + lane];
#pragma unroll
        for (int mt = 0; mt < 4; mt++)
#pragma unroll
            for (int nti = 0; nti < 2; nti++)
                acc[mt][nti] = __builtin_amdgcn_mfma_f32_16x16x32_bf16(
                    af[mt], bfr[nti], acc[mt][nti], 0, 0, 0);
    }
    // epilogue 2: bias + swish + mean over the 64 samples
#pragma unroll
    for (int nti = 0; nti < 2; nti++) {
        float tot = 0.f;
        const int o = (wv * 2 + nti) * 16 + l15;
        const float bias = b2[o];
#pragma unroll
        for (int mt = 0; mt < 4; mt++) {
#pragma unroll
            for (int r = 0; r < 4; r++) {
                float v = acc[mt][nti][r] + bias;
                tot += v / (1.f + __expf(-v));
            }
        }
        tot += __shfl_xor(tot, 16);
        tot += __shfl_xor(tot, 32);
        if (lane < 16) {
            const int oo = (wv * 2 + nti) * 16 + lane;
            out[((size_t)b * 512 + oo) * 1024 + s] = tot * 0.015625f;
        }
    }
}

extern "C" void kernel_launch(void* const* d_in, const int* in_sizes, int n_in,
                              void* d_out, int out_size, void* d_ws, size_t ws_size,
                              hipStream_t stream)
{
    const float* xyz = (const float*)d_in[0];
    const float* pts = (const float*)d_in[1];
    const float* w1  = (const float*)d_in[2];
    const float* b1  = (const float*)d_in[3];
    const float* w2  = (const float*)d_in[4];
    const float* b2  = (const float*)d_in[5];
    float* out = (float*)d_out;
    unsigned char* ws = (unsigned char*)d_ws;

    // progress counters must start negative (blocks all consumers) each call
    hipMemsetAsync((void*)(ws + OFF_PROG), 0xFF, 256, stream);
    k_prep2<<<1090, 1024, 0, stream>>>(xyz, pts, w1, w2, ws);
    k_fused<<<4100, 1024, 0, stream>>>(xyz, b1, b2, ws, out);
}

// Round 13
// 1648.586 us; speedup vs baseline: 4.0402x; 1.0673x over previous
//
#include <hip/hip_runtime.h>
#include <hip/hip_bf16.h>
#include <stdint.h>

#define BB 4
#define NN 16384
#define SS 1024
#define KSAMP 64
#define DD 256
#define CIN 259
#define HH 512
#define R2C 0.04f

// workspace offsets (bytes, all 256-aligned)
#define OFF_PTS  0ull            // bf16 pointsT [B][N][256]  33,554,432
#define OFF_Q    33554432ull     // f32 point norms [B][N]       262,144
#define OFF_W1P  33816576ull     // bf16 packed w1               294,912
#define OFF_W2P  34111488ull     // bf16 packed w2               524,288
#define OFF_CX   34635776ull     // f32 centers x [4096]
#define OFF_CY   34652160ull
#define OFF_CZ   34668544ull
#define OFF_PROG 34684928ull     // int prog[4]

typedef __attribute__((ext_vector_type(8))) short bf16x8;
typedef __attribute__((ext_vector_type(4))) short bf16x4;
typedef __attribute__((ext_vector_type(4))) float f32x4;

__device__ __forceinline__ unsigned short f2bf(float f) {
    unsigned u = __float_as_uint(f);
    u = u + 0x7fffu + ((u >> 16) & 1u);   // round-to-nearest-even
    return (unsigned short)(u >> 16);
}

// ---------------------------------------------------------------------------
// Kernel A: points transpose->bf16 (blocks 0..1023) + point norms
//           (1024..1087) + weight packing (1088,1089). Runs first, ~40 us.
// ---------------------------------------------------------------------------
__global__ __launch_bounds__(1024) void k_prep2(const float* __restrict__ xyz,
                                                const float* __restrict__ pts,
                                                const float* __restrict__ w1,
                                                const float* __restrict__ w2,
                                                unsigned char* __restrict__ ws)
{
    __shared__ __align__(16) unsigned char smem[64 * 264 * 2];
    const int blk = blockIdx.x;
    const int t   = threadIdx.x;

    if (blk < 1024) {
        // ---------------- transpose points -> bf16 rows --------------------
        const int b  = blk >> 8;
        const int n0 = (blk & 255) << 6;      // 64 points per tile
        unsigned short* sT = (unsigned short*)smem;  // [64][264]
        const int tn = t & 63, tc = t >> 6;   // tc 0..15
        for (int cc = tc; cc < 256; cc += 16) {
            float v = pts[((size_t)(b * 256 + cc)) * NN + n0 + tn];
            sT[tn * 264 + cc] = f2bf(v);
        }
        __syncthreads();
        unsigned short* ptsT = (unsigned short*)(ws + OFF_PTS);
        const int r = t >> 4, part = t & 15;  // 16 shorts per thread
        size_t ob = (((size_t)b * NN) + n0 + r) * 256 + part * 16;
        bf16x8* dst = (bf16x8*)(ptsT + ob);
        const bf16x8* src = (const bf16x8*)(sT + r * 264 + part * 16);
        dst[0] = src[0];
        dst[1] = src[1];
    } else if (blk < 1088) {
        // ---------------- point squared norms ------------------------------
        const int qb = blk - 1024;
        const int b = qb >> 4;
        const int n = ((qb & 15) << 10) + t;
        const float* xb = xyz + (size_t)b * 3 * NN;
        float X = xb[n], Y = xb[NN + n], Z = xb[2 * NN + n];
        float q = __fadd_rn(__fadd_rn(__fmul_rn(X, X), __fmul_rn(Y, Y)), __fmul_rn(Z, Z));
        ((float*)(ws + OFF_Q))[b * NN + n] = q;
    } else if (blk == 1088) {
        // ---------------- pack w1 into MFMA-B fragment order ---------------
        unsigned short* w1p = (unsigned short*)(ws + OFF_W1P);
        for (int e = t; e < 32 * 9 * 64 * 8; e += 1024) {
            int j = e & 7, lane = (e >> 3) & 63, rest = e >> 9;
            int kt = rest % 9, nt = rest / 9;
            int kk = kt * 32 + 4 * (lane >> 4) + (j & 3) + 16 * (j >> 2);
            int o  = nt * 16 + (lane & 15);
            float v = 0.f;
            if (kk < CIN) {
                int c = (kk < 256) ? (kk + 3) : (kk - 256);
                v = w1[o * CIN + c];
            }
            w1p[e] = f2bf(v);
        }
    } else {
        unsigned short* w2p = (unsigned short*)(ws + OFF_W2P);
        for (int e = t; e < 32 * 16 * 64 * 8; e += 1024) {
            int j = e & 7, lane = (e >> 3) & 63, rest = e >> 9;
            int kt = rest & 15, nt = rest >> 4;
            int kk = kt * 32 + 4 * (lane >> 4) + (j & 3) + 16 * (j >> 2);
            int o  = nt * 16 + (lane & 15);
            w2p[e] = f2bf(w2[o * 512 + kk]);
        }
    }
}

// ---------------------------------------------------------------------------
// Kernel B: blocks 0..3 = FPS producers (round-1 verbatim FPS + agent-scope
//           atomic center publication). blocks 4..4099 = per-(b,s) consumers.
// LDS map (consumer): sFeat [0,37888) | sH1 [37888,104448) | sIdx [104448,104704)
// ---------------------------------------------------------------------------
__global__ __launch_bounds__(1024) void k_fused(const float* __restrict__ xyz,
                                                const float* __restrict__ b1,
                                                const float* __restrict__ b2,
                                                unsigned char* __restrict__ ws,
                                                float* __restrict__ out)
{
    __shared__ __align__(16) unsigned char smem[104832];
    const int blk = blockIdx.x;
    const int t   = threadIdx.x;
    int* prog = (int*)(ws + OFF_PROG);
    float* cxs = (float*)(ws + OFF_CX);
    float* cys = (float*)(ws + OFF_CY);
    float* czs = (float*)(ws + OFF_CZ);

    if (blk < 4) {
        // ================= FPS producer, batch b = blk (round-1 code) ======
        const int b = blk;
        const float* xb = xyz + (size_t)b * 3 * NN;
        float x[16], y[16], z[16], d[16];
        const int base = t * 16;
        const float4* xv = (const float4*)(xb + base);
        const float4* yv = (const float4*)(xb + NN + base);
        const float4* zv = (const float4*)(xb + 2 * NN + base);
#pragma unroll
        for (int i = 0; i < 4; i++) {
            float4 a = xv[i]; x[4*i]=a.x; x[4*i+1]=a.y; x[4*i+2]=a.z; x[4*i+3]=a.w;
            float4 c = yv[i]; y[4*i]=c.x; y[4*i+1]=c.y; y[4*i+2]=c.z; y[4*i+3]=c.w;
            float4 e = zv[i]; z[4*i]=e.x; z[4*i+1]=e.y; z[4*i+2]=e.z; z[4*i+3]=e.w;
        }
#pragma unroll
        for (int i = 0; i < 16; i++) d[i] = 1e10f;

        float* sC    = (float*)smem;         // [3] centroid
        float* sWMax = (float*)smem + 4;     // [16]
        int*   sWin  = (int*)((float*)smem + 20);

        // initial farthest = b (b < 16 -> owner thread 0)
        if (t == (b >> 4)) {
#pragma unroll
            for (int k = 0; k < 16; k++)
                if ((b & 15) == k) { sC[0] = x[k]; sC[1] = y[k]; sC[2] = z[k]; }
        }
        __syncthreads();

        for (int it = 0; it < SS; ++it) {
            const float cx = sC[0], cy = sC[1], cz = sC[2];
            if (t == 0) {
                // publish center via agent-scope atomics (coherence point,
                // visible to all XCDs)
                __hip_atomic_store(&cxs[(b << 10) + it], cx, __ATOMIC_RELAXED,
                                   __HIP_MEMORY_SCOPE_AGENT);
                __hip_atomic_store(&cys[(b << 10) + it], cy, __ATOMIC_RELAXED,
                                   __HIP_MEMORY_SCOPE_AGENT);
                __hip_atomic_store(&czs[(b << 10) + it], cz, __ATOMIC_RELAXED,
                                   __HIP_MEMORY_SCOPE_AGENT);
                // release every 8th iter: orders all prior center stores
                if ((it & 7) == 0)
                    __hip_atomic_store(&prog[b], it, __ATOMIC_RELEASE,
                                       __HIP_MEMORY_SCOPE_AGENT);
                *sWin = 0x7fffffff;
            }
            if (it == SS - 1) break;

            float bl = -1.0f;
#pragma unroll
            for (int k = 0; k < 16; k++) {
                float dx = __fsub_rn(x[k], cx);
                float dy = __fsub_rn(y[k], cy);
                float dz = __fsub_rn(z[k], cz);
                float s  = __fadd_rn(__fadd_rn(__fmul_rn(dx, dx), __fmul_rn(dy, dy)),
                                     __fmul_rn(dz, dz));
                float nd = fminf(d[k], s);
                d[k] = nd;
                bl = fmaxf(bl, nd);
            }
            float bm = bl;
#pragma unroll
            for (int off = 32; off; off >>= 1) bm = fmaxf(bm, __shfl_xor(bm, off));
            if ((t & 63) == 0) sWMax[t >> 6] = bm;
            __syncthreads();

            float gm = sWMax[0];
#pragma unroll
            for (int wv = 1; wv < 16; wv++) gm = fmaxf(gm, sWMax[wv]);

            if (bl == gm) {
                int cand = 0x7fffffff;
#pragma unroll
                for (int k = 15; k >= 0; k--) if (d[k] == gm) cand = base + k;
                atomicMin(sWin, cand);
            }
            __syncthreads();
            const int w = *sWin;
            if (t == (w >> 4)) {
                const int wk = w & 15;
#pragma unroll
                for (int k = 0; k < 16; k++)
                    if (wk == k) { sC[0] = x[k]; sC[1] = y[k]; sC[2] = z[k]; }
            }
            __syncthreads();
        }
        // final: all centers written -> release everything
        if (t == 0)
            __hip_atomic_store(&prog[b], SS, __ATOMIC_RELEASE,
                               __HIP_MEMORY_SCOPE_AGENT);
        return;
    }

    // ==================== consumer block: (b, s) ===========================
    const int i = blk - 4;
    const int b = i & 3, s = i >> 2;
    const int cs = (b << 10) + s;

    unsigned short* sFeat = (unsigned short*)smem;            // [64][296] = 37,888 B
    unsigned short* sH1   = (unsigned short*)(smem + 37888);  // [64][520] = 66,560 B
    int*            sIdx  = (int*)(smem + 104448);            // [64]      =    256 B

    // ---- phase 0: wait until center s is published (prog init = -1) ----
    if (t == 0) {
        while (__hip_atomic_load(&prog[b], __ATOMIC_ACQUIRE,
                                 __HIP_MEMORY_SCOPE_AGENT) <= s)
            __builtin_amdgcn_s_sleep(8);
    }
    __syncthreads();

    // read center via agent atomics (coherence point; ordered by release)
    const float cx = __hip_atomic_load(&cxs[cs], __ATOMIC_RELAXED,
                                       __HIP_MEMORY_SCOPE_AGENT);
    const float cy = __hip_atomic_load(&cys[cs], __ATOMIC_RELAXED,
                                       __HIP_MEMORY_SCOPE_AGENT);
    const float cz = __hip_atomic_load(&czs[cs], __ATOMIC_RELAXED,
                                       __HIP_MEMORY_SCOPE_AGENT);
    const float* xb = xyz + (size_t)b * 3 * NN;

    // ---- phase 1: ball query (wave 0 only) -> sIdx ----
    if (t < 64) {
        const int lane = t;
        const float* Q = (const float*)(ws + OFF_Q) + b * NN;
        const float qc = __fadd_rn(__fadd_rn(__fmul_rn(cx, cx), __fmul_rn(cy, cy)),
                                   __fmul_rn(cz, cz));
        int collected = 0;
        int first = -1;
        for (int c = 0; c < 256; c++) {
            const int n = (c << 6) + lane;
            float px = xb[n], py = xb[NN + n], pz = xb[2 * NN + n], qj = Q[n];
            float dot = __fadd_rn(__fadd_rn(__fmul_rn(cx, px), __fmul_rn(cy, py)),
                                  __fmul_rn(cz, pz));
            float r = __fsub_rn(__fadd_rn(qc, qj), __fmul_rn(2.0f, dot));
            bool valid = !(r > R2C);
            unsigned long long m = __ballot(valid);
            if (m) {
                if (first < 0) first = (c << 6) + __builtin_ctzll(m);
                int rank = __popcll(m & ((1ull << lane) - 1ull));
                int slot = collected + rank;
                if (valid && slot < 64) sIdx[slot] = n;
                collected += __popcll(m);
                if (collected >= 64) break;
            }
        }
        if (collected < 64) {
            for (int k = collected + lane; k < 64; k += 64) sIdx[k] = first;
        }
    }
    __syncthreads();

    // ---- phase 2: gather features (FULL 256 shorts per point) ----
    {
        const unsigned short* ptsT = (const unsigned short*)(ws + OFF_PTS);
        const int k = t >> 4, part = t & 15;   // 64 pts x 16 parts x 16 shorts
        const int n = sIdx[k];
        const bf16x8* src = (const bf16x8*)(ptsT + ((size_t)b * NN + n) * 256 + part * 16);
        bf16x8* dst = (bf16x8*)(sFeat + k * 296 + part * 16);
        dst[0] = src[0];
        dst[1] = src[1];
    }
    if (t < 64) {
        const int n = sIdx[t];
        sFeat[t * 296 + 256] = f2bf(__fsub_rn(xb[n], cx));
        sFeat[t * 296 + 257] = f2bf(__fsub_rn(xb[NN + n], cy));
        sFeat[t * 296 + 258] = f2bf(__fsub_rn(xb[2 * NN + n], cz));
#pragma unroll
        for (int c = 259; c < 288; c++) sFeat[t * 296 + c] = 0;
    }
    __syncthreads();

    const int wv = t >> 6, lane = t & 63;
    const int l15 = lane & 15, g = lane >> 4;

    f32x4 acc[4][2];
#pragma unroll
    for (int a = 0; a < 4; a++)
#pragma unroll
        for (int j = 0; j < 2; j++) acc[a][j] = (f32x4){0.f, 0.f, 0.f, 0.f};

    // ---- layer 1: K = 288 (9 ktiles); 16 waves x 2 ntiles ----
    const bf16x8* w1v = (const bf16x8*)(ws + OFF_W1P);
    for (int kt = 0; kt < 9; kt++) {
        bf16x8 af[4];
#pragma unroll
        for (int mt = 0; mt < 4; mt++) {
            const unsigned short* p = sFeat + (mt * 16 + l15) * 296 + kt * 32 + 4 * g;
            bf16x4 lo = *(const bf16x4*)p;
            bf16x4 hi = *(const bf16x4*)(p + 16);
            af[mt] = __builtin_shufflevector(lo, hi, 0, 1, 2, 3, 4, 5, 6, 7);
        }
        bf16x8 bfr[2];
#pragma unroll
        for (int nti = 0; nti < 2; nti++)
            bfr[nti] = w1v[((wv * 2 + nti) * 9 + kt) * 64 + lane];
#pragma unroll
        for (int mt = 0; mt < 4; mt++)
#pragma unroll
            for (int nti = 0; nti < 2; nti++)
                acc[mt][nti] = __builtin_amdgcn_mfma_f32_16x16x32_bf16(
                    af[mt], bfr[nti], acc[mt][nti], 0, 0, 0);
    }
    // epilogue 1: bias + swish -> sH1 (bf16)
#pragma unroll
    for (int mt = 0; mt < 4; mt++)
#pragma unroll
        for (int nti = 0; nti < 2; nti++) {
            const int o = (wv * 2 + nti) * 16 + l15;
            const float bias = b1[o];
#pragma unroll
            for (int r = 0; r < 4; r++) {
                float v = acc[mt][nti][r] + bias;
                float sw = v / (1.f + __expf(-v));
                sH1[(mt * 16 + g * 4 + r) * 520 + o] = f2bf(sw);
            }
        }
    __syncthreads();

    // ---- layer 2: K = 512 (16 ktiles) ----
#pragma unroll
    for (int a = 0; a < 4; a++)
#pragma unroll
        for (int j = 0; j < 2; j++) acc[a][j] = (f32x4){0.f, 0.f, 0.f, 0.f};

    const bf16x8* w2v = (const bf16x8*)(ws + OFF_W2P);
    for (int kt = 0; kt < 16; kt++) {
        bf16x8 af[4];
#pragma unroll
        for (int mt = 0; mt < 4; mt++) {
            const unsigned short* p = sH1 + (mt * 16 + l15) * 520 + kt * 32 + 4 * g;
            bf16x4 lo = *(const bf16x4*)p;
            bf16x4 hi = *(const bf16x4*)(p + 16);
            af[mt] = __builtin_shufflevector(lo, hi, 0, 1, 2, 3, 4, 5, 6, 7);
        }
        bf16x8 bfr[2];
#pragma unroll
        for (int nti = 0; nti < 2; nti++)
            bfr[nti] = w2v[((wv * 2 + nti) * 16 + kt) * 64 + lane];
#pragma unroll
        for (int mt = 0; mt < 4; mt++)
#pragma unroll
            for (int nti = 0; nti < 2; nti++)
                acc[mt][nti] = __builtin_amdgcn_mfma_f32_16x16x32_bf16(
                    af[mt], bfr[nti], acc[mt][nti], 0, 0, 0);
    }
    // epilogue 2: bias + swish + mean over the 64 samples
#pragma unroll
    for (int nti = 0; nti < 2; nti++) {
        float tot = 0.f;
        const int o = (wv * 2 + nti) * 16 + l15;
        const float bias = b2[o];
#pragma unroll
        for (int mt = 0; mt < 4; mt++) {
#pragma unroll
            for (int r = 0; r < 4; r++) {
                float v = acc[mt][nti][r] + bias;
                tot += v / (1.f + __expf(-v));
            }
        }
        tot += __shfl_xor(tot, 16);
        tot += __shfl_xor(tot, 32);
        if (lane < 16) {
            const int oo = (wv * 2 + nti) * 16 + lane;
            out[((size_t)b * 512 + oo) * 1024 + s] = tot * 0.015625f;
        }
    }
}

extern "C" void kernel_launch(void* const* d_in, const int* in_sizes, int n_in,
                              void* d_out, int out_size, void* d_ws, size_t ws_size,
                              hipStream_t stream)
{
    const float* xyz = (const float*)d_in[0];
    const float* pts = (const float*)d_in[1];
    const float* w1  = (const float*)d_in[2];
    const float* b1  = (const float*)d_in[3];
    const float* w2  = (const float*)d_in[4];
    const float* b2  = (const float*)d_in[5];
    float* out = (float*)d_out;
    unsigned char* ws = (unsigned char*)d_ws;

    // progress counters must start negative (blocks all consumers) each call
    hipMemsetAsync((void*)(ws + OFF_PROG), 0xFF, 16, stream);
    k_prep2<<<1090, 1024, 0, stream>>>(xyz, pts, w1, w2, ws);
    k_fused<<<4100, 1024, 0, stream>>>(xyz, b1, b2, ws, out);
}